// Round 1
// baseline (11773.714 us; speedup 1.0000x reference)
//
#include <hip/hip_runtime.h>
#include <hip/hip_bf16.h>
#include <hip/hip_fp16.h>

typedef _Float16 f16;
typedef _Float16 f16x8 __attribute__((ext_vector_type(8)));
typedef float f32x4 __attribute__((ext_vector_type(4)));

#define B_ 128
#define T_ 512
#define I_ 512
#define H_ 512

// ---------------- workspace layout (bytes) ----------------
static constexpr size_t OFF_LEN   = 0;                       // 128 int
static constexpr size_t OFF_BIAS0 = 1024;                    // 2048 f32
static constexpr size_t OFF_BIAS1 = OFF_BIAS0 + 8192;        // 2048 f32
static constexpr size_t OFF_W0    = 32768;                   // 2048x1024 f16 (reordered, [w_ih|w_hh])
static constexpr size_t OFF_W1    = OFF_W0 + 4u*1024u*1024u;
static constexpr size_t OFF_H0A   = OFF_W1 + 4u*1024u*1024u; // 128x512 f16
static constexpr size_t OFF_H0B   = OFF_H0A + 131072;
static constexpr size_t OFF_H1A   = OFF_H0B + 131072;
static constexpr size_t OFF_H1B   = OFF_H1A + 131072;
static constexpr size_t OFF_C0    = OFF_H1B + 131072;        // 128x512 f32
static constexpr size_t OFF_C1    = OFF_C0 + 262144;
static constexpr size_t OFF_H1F   = OFF_C1 + 262144;         // 128x512 f32
static constexpr size_t WS_NEED   = OFF_H1F + 262144;

// ---------------- lengths: count rows with sum != 0 ----------------
__global__ __launch_bounds__(512) void k_len(const float* __restrict__ x, int* __restrict__ len) {
    int b = blockIdx.x;
    const float4* row = (const float4*)(x + ((size_t)b * T_ + threadIdx.x) * I_);
    float s = 0.f;
    #pragma unroll 4
    for (int i = 0; i < I_ / 4; ++i) { float4 v = row[i]; s += v.x + v.y + v.z + v.w; }
    int cnt = __syncthreads_count(s != 0.0f);
    if (threadIdx.x == 0) len[b] = cnt;
}

// ---------------- weight convert: reorder rows to h*4+gate, concat [w_ih|w_hh], f32->f16 ----------------
__global__ __launch_bounds__(256) void k_wcvt(const float* __restrict__ wih, const float* __restrict__ whh,
                                              const float* __restrict__ bih, const float* __restrict__ bhh,
                                              f16* __restrict__ W, float* __restrict__ bias) {
    int r = blockIdx.x;          // reordered row 0..2047
    int h = r >> 2, g = r & 3;
    int src = g * 512 + h;
    const float* a = wih + (size_t)src * 512;
    const float* bsrc = whh + (size_t)src * 512;
    f16* dst = W + (size_t)r * 1024;
    #pragma unroll
    for (int j = 0; j < 2; ++j) {
        int k = threadIdx.x + j * 256;
        dst[k]       = (f16)a[k];
        dst[k + 512] = (f16)bsrc[k];
    }
    if (threadIdx.x == 0) bias[r] = bih[src] + bhh[src];
}

// ---------------- per-timestep kernel: layer0 step t, layer1 step t-1 (pipelined) ----------------
// grid = 64 blocks (32 layer0 + 32 layer1), 512 threads (8 waves: 4 M-groups x 2 N-groups)
// Block computes gates for all 128 batch rows x 64 reordered gate-rows, K=1024 ([inA|inB]).
#define NT 64
#define KC 128

__global__ __launch_bounds__(512) void k_step(
    const float* __restrict__ x,
    const f16* __restrict__ W0, const f16* __restrict__ W1,
    const float* __restrict__ bias0, const float* __restrict__ bias1,
    const int* __restrict__ len,
    f16* __restrict__ h0a, f16* __restrict__ h0b,
    f16* __restrict__ h1a, f16* __restrict__ h1b,
    float* __restrict__ c0, float* __restrict__ c1,
    float* __restrict__ h1f, int t)
{
    __shared__ char lds[49152];   // [0,32K): A tile / gates ; [32K,48K): W tile
    int bid = blockIdx.x;
    int layer = bid >> 5;
    int nbase = (bid & 31) * NT;
    int step = layer ? (t - 1) : t;
    if (step < 0 || step >= T_) return;

    const f16* Wl = layer ? W1 : W0;
    const float* bias = layer ? bias1 : bias0;

    const f16 *inA, *inB, *h_r;
    f16* h_w;
    float* c_l;
    if (layer == 0) {
        // K [0,512): x[:,t,:] (f32, converted on the fly) ; K [512,1024): h0(t-1)
        h_r = ((t & 1) == 0) ? (const f16*)h0b : (const f16*)h0a;   // h0(t-1)
        h_w = ((t & 1) == 0) ? h0a : h0b;                           // h0(t)
        c_l = c0;
        inA = h_r;   // unused for K<512 (x path)
        inB = h_r;
    } else {
        int s = step;
        inA = ((s & 1) == 0) ? (const f16*)h0a : (const f16*)h0b;   // h0(s)
        h_r = ((s & 1) == 0) ? (const f16*)h1b : (const f16*)h1a;   // h1(s-1)
        h_w = ((s & 1) == 0) ? h1a : h1b;                           // h1(s)
        c_l = c1;
        inB = h_r;
    }

    f16* As = (f16*)lds;
    char* Wsb = lds + 32768;
    int tid = threadIdx.x;
    int wid = tid >> 6, lane = tid & 63;
    int wm = wid >> 1, wn = wid & 1;

    f32x4 acc[2][2] = {};

    for (int ch = 0; ch < 8; ++ch) {
        // ---- stage A: 128 rows x 128 cols f16, XOR-swizzled 16B granules
        {
            int row = tid >> 2, q = tid & 3;     // 32 cols per thread
            int kglob = ch * KC + q * 32;
            char* dst0 = (char*)As + row * 256;
            if (layer == 0 && kglob < 512) {
                const float4* src = (const float4*)(x + ((size_t)row * T_ + t) * I_ + kglob);
                #pragma unroll
                for (int j = 0; j < 4; ++j) {
                    float4 v0 = src[2 * j], v1 = src[2 * j + 1];
                    f16x8 hv = { (f16)v0.x, (f16)v0.y, (f16)v0.z, (f16)v0.w,
                                 (f16)v1.x, (f16)v1.y, (f16)v1.z, (f16)v1.w };
                    int byte = (q * 32 + j * 8) * 2;
                    *(f16x8*)(dst0 + (byte ^ ((row & 7) << 4))) = hv;
                }
            } else {
                const f16* srcv = (kglob < 512) ? (inA + (size_t)row * 512 + kglob)
                                                : (inB + (size_t)row * 512 + (kglob - 512));
                #pragma unroll
                for (int j = 0; j < 4; ++j) {
                    f16x8 hv = *(const f16x8*)(srcv + j * 8);
                    int byte = (q * 32 + j * 8) * 2;
                    *(f16x8*)(dst0 + (byte ^ ((row & 7) << 4))) = hv;
                }
            }
        }
        // ---- stage W: 64 rows x 128 cols f16
        {
            int r = tid >> 3, e = tid & 7;
            const f16* src = Wl + (size_t)(nbase + r) * 1024 + ch * KC + e * 16;
            char* dst0 = Wsb + r * 256;
            int byte = e * 32;
            *(f16x8*)(dst0 + ( byte       ^ ((r & 7) << 4))) = *(const f16x8*)src;
            *(f16x8*)(dst0 + ((byte + 16) ^ ((r & 7) << 4))) = *(const f16x8*)(src + 8);
        }
        __syncthreads();
        // ---- MFMA: 4 K-steps of 32
        #pragma unroll
        for (int ks = 0; ks < 4; ++ks) {
            int koff = ks * 32 + ((lane >> 4) << 3);
            int m0 = wm * 32 + (lane & 15);
            int m1 = m0 + 16;
            int r0 = wn * 32 + (lane & 15);
            int r1 = r0 + 16;
            f16x8 a0 = *(f16x8*)((char*)As + ((m0 * 256 + koff * 2) ^ ((m0 & 7) << 4)));
            f16x8 a1 = *(f16x8*)((char*)As + ((m1 * 256 + koff * 2) ^ ((m1 & 7) << 4)));
            f16x8 b0 = *(f16x8*)(Wsb + ((r0 * 256 + koff * 2) ^ ((r0 & 7) << 4)));
            f16x8 b1 = *(f16x8*)(Wsb + ((r1 * 256 + koff * 2) ^ ((r1 & 7) << 4)));
            acc[0][0] = __builtin_amdgcn_mfma_f32_16x16x32_f16(a0, b0, acc[0][0], 0, 0, 0);
            acc[1][0] = __builtin_amdgcn_mfma_f32_16x16x32_f16(a1, b0, acc[1][0], 0, 0, 0);
            acc[0][1] = __builtin_amdgcn_mfma_f32_16x16x32_f16(a0, b1, acc[0][1], 0, 0, 0);
            acc[1][1] = __builtin_amdgcn_mfma_f32_16x16x32_f16(a1, b1, acc[1][1], 0, 0, 0);
        }
        __syncthreads();
    }

    // ---- epilogue: gates -> LDS (f32 [128][64], swizzled), then activations + state update
    float* Gs = (float*)lds;
    #pragma unroll
    for (int mf = 0; mf < 2; ++mf)
        #pragma unroll
        for (int nf = 0; nf < 2; ++nf) {
            int n = wn * 32 + nf * 16 + (lane & 15);
            int mb = wm * 32 + mf * 16 + ((lane >> 4) << 2);
            #pragma unroll
            for (int r = 0; r < 4; ++r) {
                int m = mb + r;
                *(float*)((char*)Gs + ((m * 256 + n * 4) ^ ((m & 7) << 4))) = acc[mf][nf][r];
            }
        }
    __syncthreads();

    {
        int b = tid & 127;
        int g4 = tid >> 7;                 // 0..3
        int lb = len[b];
        bool msk = step < lb;
        #pragma unroll
        for (int u = 0; u < 4; ++u) {
            int h = g4 * 4 + u;            // 0..15 (local h unit)
            f32x4 gv = *(f32x4*)((char*)Gs + ((b * 256 + h * 16) ^ ((b & 7) << 4)));
            int rglob = nbase + h * 4;
            const float4 bb = *(const float4*)(bias + rglob);
            float gi = gv[0] + bb.x, gf = gv[1] + bb.y, gg = gv[2] + bb.z, go = gv[3] + bb.w;
            int hg = (nbase >> 2) + h;     // global h unit 0..511
            size_t idx = (size_t)b * 512 + hg;
            float co = c_l[idx];
            float si = 1.f / (1.f + expf(-gi));
            float sf = 1.f / (1.f + expf(-gf));
            float sg = tanhf(gg);
            float so = 1.f / (1.f + expf(-go));
            float cn = sf * co + si * sg;
            float hn = so * tanhf(cn);
            if (msk) {
                c_l[idx] = cn;
                h_w[idx] = (f16)hn;
                if (layer) h1f[idx] = hn;
            } else {
                h_w[idx] = h_r[idx];
            }
        }
    }
}

// ---------------- final FC: out[b][o] = h1 . w_fc[o] + b_fc[o] ----------------
__global__ __launch_bounds__(256) void k_fc(const float* __restrict__ h1f,
                                            const float* __restrict__ wfc,
                                            const float* __restrict__ bfc,
                                            float* __restrict__ out) {
    int b = blockIdx.x;
    float s0 = 0, s1 = 0, s2 = 0, s3 = 0;
    for (int h = threadIdx.x; h < 512; h += 256) {
        float v = h1f[(size_t)b * 512 + h];
        s0 += v * wfc[h];
        s1 += v * wfc[512 + h];
        s2 += v * wfc[1024 + h];
        s3 += v * wfc[1536 + h];
    }
    #pragma unroll
    for (int off = 32; off; off >>= 1) {
        s0 += __shfl_down(s0, off);
        s1 += __shfl_down(s1, off);
        s2 += __shfl_down(s2, off);
        s3 += __shfl_down(s3, off);
    }
    __shared__ float red[4][4];
    int wid = threadIdx.x >> 6;
    if ((threadIdx.x & 63) == 0) { red[wid][0] = s0; red[wid][1] = s1; red[wid][2] = s2; red[wid][3] = s3; }
    __syncthreads();
    if (threadIdx.x < 4) {
        float s = red[0][threadIdx.x] + red[1][threadIdx.x] + red[2][threadIdx.x] + red[3][threadIdx.x]
                + bfc[threadIdx.x];
        out[b * 4 + threadIdx.x] = s;
    }
}

extern "C" void kernel_launch(void* const* d_in, const int* in_sizes, int n_in,
                              void* d_out, int out_size, void* d_ws, size_t ws_size,
                              hipStream_t stream) {
    const float* x    = (const float*)d_in[0];
    const float* wih0 = (const float*)d_in[1];
    const float* whh0 = (const float*)d_in[2];
    const float* bih0 = (const float*)d_in[3];
    const float* bhh0 = (const float*)d_in[4];
    const float* wih1 = (const float*)d_in[5];
    const float* whh1 = (const float*)d_in[6];
    const float* bih1 = (const float*)d_in[7];
    const float* bhh1 = (const float*)d_in[8];
    const float* wfc  = (const float*)d_in[9];
    const float* bfc  = (const float*)d_in[10];

    if (ws_size < WS_NEED) return;  // should not happen (needs ~9.3 MB)

    char* ws = (char*)d_ws;
    int*   len   = (int*)(ws + OFF_LEN);
    float* bias0 = (float*)(ws + OFF_BIAS0);
    float* bias1 = (float*)(ws + OFF_BIAS1);
    f16*   W0    = (f16*)(ws + OFF_W0);
    f16*   W1    = (f16*)(ws + OFF_W1);
    f16*   h0a   = (f16*)(ws + OFF_H0A);
    f16*   h0b   = (f16*)(ws + OFF_H0B);
    f16*   h1a   = (f16*)(ws + OFF_H1A);
    f16*   h1b   = (f16*)(ws + OFF_H1B);
    float* c0    = (float*)(ws + OFF_C0);
    float* c1    = (float*)(ws + OFF_C1);
    float* h1f   = (float*)(ws + OFF_H1F);

    // zero all recurrent state (h0a..h1f contiguous = 1310720 bytes)
    hipMemsetAsync(ws + OFF_H0A, 0, WS_NEED - OFF_H0A, stream);

    k_len<<<B_, 512, 0, stream>>>(x, len);
    k_wcvt<<<2048, 256, 0, stream>>>(wih0, whh0, bih0, bhh0, W0, bias0);
    k_wcvt<<<2048, 256, 0, stream>>>(wih1, whh1, bih1, bhh1, W1, bias1);

    for (int t = 0; t <= T_; ++t)
        k_step<<<64, 512, 0, stream>>>(x, W0, W1, bias0, bias1, len,
                                       h0a, h0b, h1a, h1b, c0, c1, h1f, t);

    k_fc<<<B_, 256, 0, stream>>>(h1f, wfc, bfc, (float*)d_out);
}